// Round 1
// baseline (630.425 us; speedup 1.0000x reference)
//
#include <hip/hip_runtime.h>
#include <math.h>

namespace {
constexpr int kB = 16;
constexpr int kT = 120;
constexpr int kP = 96;
constexpr int kD = 128;
constexpr int kBT = kB * kT;        // 1920
constexpr int kPP = kP * kP;        // 9216
constexpr int kPD = kP * kD;        // 12288
constexpr long long kND = (long long)kBT * kPP;  // 17,694,720

constexpr int Y_STRIDE = 132;       // padded row stride for y/h tiles in LDS
constexpr int A_STRIDE = 100;       // padded row stride for adj tile in LDS
}

// ---------------------------------------------------------------------------
// Kernel 1: canonicalize padding mask (layout-detecting) + zero stats accums.
// counts[b] >= 48, so mask[0..1] are 1 in every layout -> first word detects.
// ---------------------------------------------------------------------------
__global__ void k_mask(const unsigned char* __restrict__ mraw, int* __restrict__ mask,
                       double* __restrict__ stats) {
    int tid = threadIdx.x;
    if (tid < 4) stats[tid] = 0.0;
    const unsigned int* u32 = (const unsigned int*)mraw;
    unsigned int w0 = u32[0];
    int mode;
    if (w0 == 0x01010101u) mode = 0;       // 1-byte bool
    else if (w0 == 1u) mode = 1;           // int32
    else mode = 2;                          // float32
    for (int i = tid; i < kB * kP; i += blockDim.x) {
        int v;
        if (mode == 0)      v = (mraw[i] != 0);
        else if (mode == 1) v = (u32[i] != 0);
        else                v = (((const float*)mraw)[i] != 0.0f);
        mask[i] = v;
    }
}

// ---------------------------------------------------------------------------
// Kernel 2: global masked stats over distances: sum, sumsq, count (doubles).
// pos == vm since distances >= 1e-6 > 0.
// ---------------------------------------------------------------------------
__global__ __launch_bounds__(256) void k_stats(const float* __restrict__ dist,
                                               const int* __restrict__ mask,
                                               double* __restrict__ stats) {
    long long stride = (long long)gridDim.x * blockDim.x;
    double s = 0.0, s2 = 0.0, cn = 0.0;
    for (long long idx = (long long)blockIdx.x * blockDim.x + threadIdx.x; idx < kND;
         idx += stride) {
        int q = (int)(idx % kP);
        long long r = idx / kP;
        int p = (int)(r % kP);
        int bt = (int)(r / kP);
        int b = bt / kT;
        if (mask[b * kP + p] && mask[b * kP + q]) {
            double d = (double)dist[idx];
            s += d;
            s2 += d * d;
            cn += 1.0;
        }
    }
    __shared__ double sh[256];
    int tid = threadIdx.x;
    sh[tid] = s; __syncthreads();
    for (int off = 128; off > 0; off >>= 1) { if (tid < off) sh[tid] += sh[tid + off]; __syncthreads(); }
    if (tid == 0) atomicAdd(&stats[0], sh[0]);
    __syncthreads();
    sh[tid] = s2; __syncthreads();
    for (int off = 128; off > 0; off >>= 1) { if (tid < off) sh[tid] += sh[tid + off]; __syncthreads(); }
    if (tid == 0) atomicAdd(&stats[1], sh[0]);
    __syncthreads();
    sh[tid] = cn; __syncthreads();
    for (int off = 128; off > 0; off >>= 1) { if (tid < off) sh[tid] += sh[tid + off]; __syncthreads(); }
    if (tid == 0) atomicAdd(&stats[2], sh[0]);
}

// ---------------------------------------------------------------------------
// Kernel 3: finalize sigma -> 1/(2*sigma^2)
// ---------------------------------------------------------------------------
__global__ void k_fin(const double* __restrict__ stats, float* __restrict__ params) {
    double n = stats[2];
    double mean = stats[0] / n;
    double var = (stats[1] - n * mean * mean) / (n - 1.0);
    double sigma = sqrt(var) + 1e-8;
    params[0] = (float)(1.0 / (2.0 * sigma * sigma));
}

// ---------------------------------------------------------------------------
// Kernel 4: adjacency build, one block per (b,t). 96x96 tile in LDS.
// ---------------------------------------------------------------------------
__global__ __launch_bounds__(256) void k_adj(const float* __restrict__ dist,
                                             const int* __restrict__ mask,
                                             const float* __restrict__ params,
                                             float* __restrict__ adj) {
    __shared__ float aT[kP * 97];
    __shared__ float dis[kP];
    __shared__ int mrow[kP];
    int bt = blockIdx.x;
    int b = bt / kT;
    int tid = threadIdx.x;
    if (tid < kP) mrow[tid] = mask[b * kP + tid];
    float inv2s2 = params[0];
    __syncthreads();
    const float* dbt = dist + (long long)bt * kPP;
    #pragma unroll
    for (int k = 0; k < 36; ++k) {
        int e = k * 256 + tid;
        int p = e / kP;
        int q = e - p * kP;
        float d = dbt[e];
        float v = 0.0f;
        if (mrow[p] && mrow[q]) v = __expf(-d * d * inv2s2);
        if (p == q && mrow[p]) v += 1.0f;
        aT[p * 97 + q] = v;
    }
    __syncthreads();
    if (tid < kP) {
        float s = 0.0f;
        for (int q = 0; q < kP; ++q) s += aT[tid * 97 + q];
        s = fmaxf(s, 1e-8f);                       // clip(deg)
        s = fmaxf(s * (float)mrow[tid], 1e-8f);    // clip(deg*mask)
        dis[tid] = 1.0f / sqrtf(s);                // deg^-0.5
    }
    __syncthreads();
    float* obt = adj + (long long)bt * kPP;
    #pragma unroll
    for (int k = 0; k < 36; ++k) {
        int e = k * 256 + tid;
        int p = e / kP;
        int q = e - p * kP;
        obt[e] = dis[p] * aT[p * 97 + q] * dis[q];
    }
}

// ---------------------------------------------------------------------------
// Kernel 5/7: transposes (B, PD, T) <-> (B, T, PD), tiled 32x32 via LDS.
// ---------------------------------------------------------------------------
__global__ void k_tin(const float* __restrict__ x, float* __restrict__ y) {
    __shared__ float tile[32][33];
    int b = blockIdx.z;
    int r0 = blockIdx.x * 32;   // PD index
    int t0 = blockIdx.y * 32;   // T index
    int tx = threadIdx.x, ty = threadIdx.y;
    #pragma unroll
    for (int i = ty; i < 32; i += 8) {
        int t = t0 + tx;
        if (t < kT) tile[i][tx] = x[((long long)b * kPD + (r0 + i)) * kT + t];
    }
    __syncthreads();
    #pragma unroll
    for (int i = ty; i < 32; i += 8) {
        int t = t0 + i;
        if (t < kT) y[((long long)b * kT + t) * kPD + (r0 + tx)] = tile[tx][i];
    }
}

__global__ void k_tout(const float* __restrict__ y, float* __restrict__ out) {
    __shared__ float tile[32][33];
    int b = blockIdx.z;
    int r0 = blockIdx.x * 32;
    int t0 = blockIdx.y * 32;
    int tx = threadIdx.x, ty = threadIdx.y;
    #pragma unroll
    for (int i = ty; i < 32; i += 8) {
        int t = t0 + i;
        if (t < kT) tile[i][tx] = y[((long long)b * kT + t) * kPD + (r0 + tx)];
    }
    __syncthreads();
    #pragma unroll
    for (int i = ty; i < 32; i += 8) {
        int t = t0 + tx;
        if (t < kT) out[((long long)b * kPD + (r0 + i)) * kT + t] = tile[tx][i];
    }
}

// ---------------------------------------------------------------------------
// Kernel 6: fused GCN layer, one block per (b,t).
//   h = y_bt * W    (96x128 = 96x128 * 128x128), W staged in 32-row chunks
//   o = adj_bt * h  (96x128 = 96x96 * 96x128)
//   y_bt += LN_D(relu(o + b) * mask_p) * gamma + beta
// Thread grid 16(ty:p) x 16(tx:d). Micro-tile: 6 rows x (4 + 4) cols
// (cols tx*4..+3 and 64+tx*4..+3 -> 2-way LDS broadcast, conflict-free).
// ---------------------------------------------------------------------------
__global__ __launch_bounds__(256, 1) void k_layer(float* __restrict__ y,
                                                  const float* __restrict__ adj,
                                                  const int* __restrict__ mask,
                                                  const float* __restrict__ Wl,
                                                  const float* __restrict__ bl,
                                                  const float* __restrict__ gl,
                                                  const float* __restrict__ btl) {
    __shared__ float yL[kP * Y_STRIDE];   // 50688 B
    __shared__ float hL[kP * Y_STRIDE];   // 50688 B
    __shared__ float aL[kP * A_STRIDE];   // 38400 B
    __shared__ float wL[32 * kD];         // 16384 B
    __shared__ int mrow[kP];              // total ~156.5 KB

    int bt = blockIdx.x;
    int b = bt / kT;
    int tid = threadIdx.x;
    int tx = tid & 15;
    int ty = tid >> 4;
    int tx4 = tx * 4;

    float* ybt = y + (long long)bt * kPD;
    const float* abt = adj + (long long)bt * kPP;

    if (tid < kP) mrow[tid] = mask[b * kP + tid];

    // stage y tile (12288 floats, float4, padded stride)
    #pragma unroll
    for (int k = 0; k < 12; ++k) {
        int e = (k * 256 + tid) * 4;
        int p = e >> 7;
        int d = e & 127;
        float4 v = *(const float4*)(ybt + e);
        *(float4*)(&yL[p * Y_STRIDE + d]) = v;
    }
    // stage adj tile (9216 floats)
    #pragma unroll
    for (int k = 0; k < 9; ++k) {
        int e = (k * 256 + tid) * 4;
        int p = e / kP;
        int q = e - p * kP;
        float4 v = *(const float4*)(abt + e);
        *(float4*)(&aL[p * A_STRIDE + q]) = v;
    }

    int yrow[6], arow[6];
    #pragma unroll
    for (int i = 0; i < 6; ++i) {
        yrow[i] = (ty * 6 + i) * Y_STRIDE;
        arow[i] = (ty * 6 + i) * A_STRIDE;
    }

    float acc[6][8];
    #pragma unroll
    for (int i = 0; i < 6; ++i)
        #pragma unroll
        for (int j = 0; j < 8; ++j) acc[i][j] = 0.0f;

    // ---- GEMM1: h = y * W, K = 128 in 4 chunks of 32 ----
    for (int kc = 0; kc < 4; ++kc) {
        __syncthreads();  // covers initial yL/aL staging (kc==0) and wL reuse
        #pragma unroll
        for (int k = 0; k < 4; ++k) {
            int e = (k * 256 + tid) * 4;
            *(float4*)(&wL[e]) = *(const float4*)(Wl + kc * 4096 + e);
        }
        __syncthreads();
        #pragma unroll
        for (int kk = 0; kk < 32; ++kk) {
            int kg = kc * 32 + kk;
            float a0 = yL[yrow[0] + kg];
            float a1 = yL[yrow[1] + kg];
            float a2 = yL[yrow[2] + kg];
            float a3 = yL[yrow[3] + kg];
            float a4 = yL[yrow[4] + kg];
            float a5 = yL[yrow[5] + kg];
            float4 b0 = *(const float4*)(&wL[kk * kD + tx4]);
            float4 b1 = *(const float4*)(&wL[kk * kD + 64 + tx4]);
            float av[6] = {a0, a1, a2, a3, a4, a5};
            #pragma unroll
            for (int i = 0; i < 6; ++i) {
                acc[i][0] = fmaf(av[i], b0.x, acc[i][0]);
                acc[i][1] = fmaf(av[i], b0.y, acc[i][1]);
                acc[i][2] = fmaf(av[i], b0.z, acc[i][2]);
                acc[i][3] = fmaf(av[i], b0.w, acc[i][3]);
                acc[i][4] = fmaf(av[i], b1.x, acc[i][4]);
                acc[i][5] = fmaf(av[i], b1.y, acc[i][5]);
                acc[i][6] = fmaf(av[i], b1.z, acc[i][6]);
                acc[i][7] = fmaf(av[i], b1.w, acc[i][7]);
            }
        }
    }

    // stage h into LDS
    #pragma unroll
    for (int i = 0; i < 6; ++i) {
        *(float4*)(&hL[yrow[i] + tx4]) = make_float4(acc[i][0], acc[i][1], acc[i][2], acc[i][3]);
        *(float4*)(&hL[yrow[i] + 64 + tx4]) = make_float4(acc[i][4], acc[i][5], acc[i][6], acc[i][7]);
    }
    __syncthreads();

    // ---- GEMM2: o = adj * h, K = 96 (accumulators reused) ----
    #pragma unroll
    for (int i = 0; i < 6; ++i)
        #pragma unroll
        for (int j = 0; j < 8; ++j) acc[i][j] = 0.0f;

    for (int q = 0; q < kP; ++q) {
        float4 b0 = *(const float4*)(&hL[q * Y_STRIDE + tx4]);
        float4 b1 = *(const float4*)(&hL[q * Y_STRIDE + 64 + tx4]);
        #pragma unroll
        for (int i = 0; i < 6; ++i) {
            float av = aL[arow[i] + q];
            acc[i][0] = fmaf(av, b0.x, acc[i][0]);
            acc[i][1] = fmaf(av, b0.y, acc[i][1]);
            acc[i][2] = fmaf(av, b0.z, acc[i][2]);
            acc[i][3] = fmaf(av, b0.w, acc[i][3]);
            acc[i][4] = fmaf(av, b1.x, acc[i][4]);
            acc[i][5] = fmaf(av, b1.y, acc[i][5]);
            acc[i][6] = fmaf(av, b1.z, acc[i][6]);
            acc[i][7] = fmaf(av, b1.w, acc[i][7]);
        }
    }

    // ---- epilogue: relu + bias + mask, LayerNorm over D, residual add ----
    float4 bb0 = *(const float4*)(bl + tx4);
    float4 bb1 = *(const float4*)(bl + 64 + tx4);
    float4 g0 = *(const float4*)(gl + tx4);
    float4 g1 = *(const float4*)(gl + 64 + tx4);
    float4 be0 = *(const float4*)(btl + tx4);
    float4 be1 = *(const float4*)(btl + 64 + tx4);

    #pragma unroll
    for (int i = 0; i < 6; ++i) {
        int p = ty * 6 + i;
        float mpf = (float)mrow[p];
        float v[8];
        v[0] = fmaxf(acc[i][0] + bb0.x, 0.0f) * mpf;
        v[1] = fmaxf(acc[i][1] + bb0.y, 0.0f) * mpf;
        v[2] = fmaxf(acc[i][2] + bb0.z, 0.0f) * mpf;
        v[3] = fmaxf(acc[i][3] + bb0.w, 0.0f) * mpf;
        v[4] = fmaxf(acc[i][4] + bb1.x, 0.0f) * mpf;
        v[5] = fmaxf(acc[i][5] + bb1.y, 0.0f) * mpf;
        v[6] = fmaxf(acc[i][6] + bb1.z, 0.0f) * mpf;
        v[7] = fmaxf(acc[i][7] + bb1.w, 0.0f) * mpf;

        float s = v[0] + v[1] + v[2] + v[3] + v[4] + v[5] + v[6] + v[7];
        s += __shfl_xor(s, 8);
        s += __shfl_xor(s, 4);
        s += __shfl_xor(s, 2);
        s += __shfl_xor(s, 1);
        float mu = s * 0.0078125f;  // /128

        float ss = 0.0f;
        #pragma unroll
        for (int j = 0; j < 8; ++j) {
            float dv = v[j] - mu;
            ss += dv * dv;
        }
        ss += __shfl_xor(ss, 8);
        ss += __shfl_xor(ss, 4);
        ss += __shfl_xor(ss, 2);
        ss += __shfl_xor(ss, 1);
        float inv = rsqrtf(ss * 0.0078125f + 1e-5f);

        float o0 = yL[p * Y_STRIDE + tx4 + 0] + (v[0] - mu) * inv * g0.x + be0.x;
        float o1 = yL[p * Y_STRIDE + tx4 + 1] + (v[1] - mu) * inv * g0.y + be0.y;
        float o2 = yL[p * Y_STRIDE + tx4 + 2] + (v[2] - mu) * inv * g0.z + be0.z;
        float o3 = yL[p * Y_STRIDE + tx4 + 3] + (v[3] - mu) * inv * g0.w + be0.w;
        float o4 = yL[p * Y_STRIDE + 64 + tx4 + 0] + (v[4] - mu) * inv * g1.x + be1.x;
        float o5 = yL[p * Y_STRIDE + 64 + tx4 + 1] + (v[5] - mu) * inv * g1.y + be1.y;
        float o6 = yL[p * Y_STRIDE + 64 + tx4 + 2] + (v[6] - mu) * inv * g1.z + be1.z;
        float o7 = yL[p * Y_STRIDE + 64 + tx4 + 3] + (v[7] - mu) * inv * g1.w + be1.w;

        *(float4*)(ybt + p * kD + tx4) = make_float4(o0, o1, o2, o3);
        *(float4*)(ybt + p * kD + 64 + tx4) = make_float4(o4, o5, o6, o7);
    }
}

// ---------------------------------------------------------------------------
extern "C" void kernel_launch(void* const* d_in, const int* in_sizes, int n_in,
                              void* d_out, int out_size, void* d_ws, size_t ws_size,
                              hipStream_t stream) {
    (void)in_sizes; (void)n_in; (void)out_size; (void)ws_size;

    const float* x = (const float*)d_in[0];
    const float* dist = (const float*)d_in[1];
    const unsigned char* mraw = (const unsigned char*)d_in[2];
    const float* W = (const float*)d_in[3];
    const float* bias = (const float*)d_in[4];
    const float* gamma = (const float*)d_in[5];
    const float* beta = (const float*)d_in[6];
    float* out = (float*)d_out;

    char* ws = (char*)d_ws;
    double* stats = (double*)ws;                       // 32 B
    float* params = (float*)(ws + 32);                 // 16 B
    int* mask = (int*)(ws + 64);                       // 6144 B
    float* adj = (float*)(ws + 8192);                  // 70,778,880 B
    float* y = (float*)(ws + 8192 + (size_t)kBT * kPP * 4);  // 94,371,840 B

    k_mask<<<1, 256, 0, stream>>>(mraw, mask, stats);
    k_stats<<<2048, 256, 0, stream>>>(dist, mask, stats);
    k_fin<<<1, 1, 0, stream>>>(stats, params);
    k_adj<<<kBT, 256, 0, stream>>>(dist, mask, params, adj);

    dim3 tgrid(kPD / 32, (kT + 31) / 32, kB);
    dim3 tblk(32, 8);
    k_tin<<<tgrid, tblk, 0, stream>>>(x, y);

    for (int l = 0; l < 2; ++l) {
        k_layer<<<kBT, 256, 0, stream>>>(y, adj, mask, W + l * kD * kD, bias + l * kD,
                                         gamma + l * kD, beta + l * kD);
    }

    k_tout<<<tgrid, tblk, 0, stream>>>(y, out);
}

// Round 2
// 256.493 us; speedup vs baseline: 2.4579x; 2.4579x over previous
//
#include <hip/hip_runtime.h>
#include <math.h>

typedef __bf16 bf16_t;
typedef __bf16 bf16x8 __attribute__((ext_vector_type(8)));
typedef __bf16 bf16x4 __attribute__((ext_vector_type(4)));
typedef float f32x4 __attribute__((ext_vector_type(4)));

namespace {
constexpr int kB = 16;
constexpr int kT = 120;
constexpr int kP = 96;
constexpr int kD = 128;
constexpr int kBT = kB * kT;        // 1920
constexpr int kPP = kP * kP;        // 9216
constexpr int kPD = kP * kD;        // 12288
constexpr long long kND = (long long)kBT * kPP;  // 17,694,720

// LDS strides (elements)
constexpr int YS = 136;   // yL bf16 [96][136]  = 26112 B
constexpr int HS = 104;   // hT bf16 [128][104] = 26624 B
constexpr int AS = 104;   // aL bf16 [96][104]  = 19968 B
constexpr int OS = 132;   // oL f32  [96][132]  = 50688 B (overlays yL+hT)
}

__device__ __forceinline__ f32x4 mfma16(bf16x8 a, bf16x8 b, f32x4 c) {
    return __builtin_amdgcn_mfma_f32_16x16x32_bf16(a, b, c, 0, 0, 0);
}

// ---------------------------------------------------------------------------
// Kernel 1: canonicalize padding mask (layout-detecting) + zero stats accums.
// counts[b] >= 48, so mask[0..3] are all 1 in every layout -> word 0 detects.
// ---------------------------------------------------------------------------
__global__ void k_mask(const unsigned char* __restrict__ mraw, int* __restrict__ mask,
                       double* __restrict__ stats) {
    int tid = threadIdx.x;
    if (tid < 4) stats[tid] = 0.0;
    const unsigned int* u32 = (const unsigned int*)mraw;
    unsigned int w0 = u32[0];
    int mode;
    if (w0 == 0x01010101u) mode = 0;       // 1-byte bool
    else if (w0 == 1u) mode = 1;           // int32
    else mode = 2;                          // float32
    for (int i = tid; i < kB * kP; i += blockDim.x) {
        int v;
        if (mode == 0)      v = (mraw[i] != 0);
        else if (mode == 1) v = (u32[i] != 0);
        else                v = (((const float*)mraw)[i] != 0.0f);
        mask[i] = v;
    }
}

// ---------------------------------------------------------------------------
// Kernel 2: W[l][k][n] (f32) -> wT[l][n][k] (bf16)
// ---------------------------------------------------------------------------
__global__ void k_prep(const float* __restrict__ W, bf16_t* __restrict__ wT) {
    int l = blockIdx.y;
    int idx = blockIdx.x * 256 + threadIdx.x;   // 0..16383
    int n = idx >> 7, k = idx & 127;
    wT[l * 16384 + n * 128 + k] = (bf16_t)W[l * 16384 + k * 128 + n];
}

// ---------------------------------------------------------------------------
// Kernel 3: global masked stats over distances (float4 loads, LDS mask).
// pos == vm since distances >= 1e-6 > 0.
// ---------------------------------------------------------------------------
__global__ __launch_bounds__(256) void k_stats(const float* __restrict__ dist,
                                               const int* __restrict__ mask,
                                               double* __restrict__ stats) {
    __shared__ int ml[kB * kP];
    for (int i = threadIdx.x; i < kB * kP; i += 256) ml[i] = mask[i];
    __syncthreads();

    long long n4 = kND / 4;
    long long stride = (long long)gridDim.x * 256;
    double s = 0.0, s2 = 0.0;
    int cnt = 0;
    for (long long i4 = (long long)blockIdx.x * 256 + threadIdx.x; i4 < n4; i4 += stride) {
        int q0 = 4 * (int)(i4 % 24);
        long long r = i4 / 24;          // = (4*i4)/96
        int p = (int)(r % 96);
        int b = (int)((r / 96) / kT);
        const int* mb = ml + b * kP;
        if (mb[p]) {
            float4 d4 = *(const float4*)(dist + i4 * 4);
            if (mb[q0 + 0]) { s += d4.x; s2 += (double)d4.x * d4.x; cnt++; }
            if (mb[q0 + 1]) { s += d4.y; s2 += (double)d4.y * d4.y; cnt++; }
            if (mb[q0 + 2]) { s += d4.z; s2 += (double)d4.z * d4.z; cnt++; }
            if (mb[q0 + 3]) { s += d4.w; s2 += (double)d4.w * d4.w; cnt++; }
        }
    }
    __shared__ double sh[256];
    int tid = threadIdx.x;
    sh[tid] = s; __syncthreads();
    for (int off = 128; off > 0; off >>= 1) { if (tid < off) sh[tid] += sh[tid + off]; __syncthreads(); }
    if (tid == 0) atomicAdd(&stats[0], sh[0]);
    __syncthreads();
    sh[tid] = s2; __syncthreads();
    for (int off = 128; off > 0; off >>= 1) { if (tid < off) sh[tid] += sh[tid + off]; __syncthreads(); }
    if (tid == 0) atomicAdd(&stats[1], sh[0]);
    __syncthreads();
    sh[tid] = (double)cnt; __syncthreads();
    for (int off = 128; off > 0; off >>= 1) { if (tid < off) sh[tid] += sh[tid + off]; __syncthreads(); }
    if (tid == 0) atomicAdd(&stats[2], sh[0]);
}

// ---------------------------------------------------------------------------
// Kernel 4: finalize sigma -> 1/(2*sigma^2)
// ---------------------------------------------------------------------------
__global__ void k_fin(const double* __restrict__ stats, float* __restrict__ params) {
    double n = stats[2];
    double mean = stats[0] / n;
    double var = (stats[1] - n * mean * mean) / (n - 1.0);
    double sigma = sqrt(var) + 1e-8;
    params[0] = (float)(1.0 / (2.0 * sigma * sigma));
}

// ---------------------------------------------------------------------------
// Kernel 5: adjacency build, one block per (b,t). Output bf16.
// ---------------------------------------------------------------------------
__global__ __launch_bounds__(256) void k_adj(const float* __restrict__ dist,
                                             const int* __restrict__ mask,
                                             const float* __restrict__ params,
                                             bf16_t* __restrict__ adj) {
    __shared__ float aT[kP * 97];
    __shared__ float dis[kP];
    __shared__ int mrow[kP];
    int bt = blockIdx.x;
    int b = bt / kT;
    int tid = threadIdx.x;
    if (tid < kP) mrow[tid] = mask[b * kP + tid];
    float inv2s2 = params[0];
    __syncthreads();
    const float* dbt = dist + (long long)bt * kPP;
    #pragma unroll
    for (int k = 0; k < 36; ++k) {
        int e = k * 256 + tid;
        int p = e / kP;
        int q = e - p * kP;
        float d = dbt[e];
        float v = 0.0f;
        if (mrow[p] && mrow[q]) v = __expf(-d * d * inv2s2);
        if (p == q && mrow[p]) v += 1.0f;
        aT[p * 97 + q] = v;
    }
    __syncthreads();
    if (tid < kP) {
        float s = 0.0f;
        for (int q = 0; q < kP; ++q) s += aT[tid * 97 + q];
        s = fmaxf(s, 1e-8f);
        s = fmaxf(s * (float)mrow[tid], 1e-8f);
        dis[tid] = 1.0f / sqrtf(s);
    }
    __syncthreads();
    bf16_t* obt = adj + (long long)bt * kPP;
    #pragma unroll
    for (int k = 0; k < 36; ++k) {
        int e = k * 256 + tid;
        int p = e / kP;
        int q = e - p * kP;
        obt[e] = (bf16_t)(dis[p] * aT[p * 97 + q] * dis[q]);
    }
}

// ---------------------------------------------------------------------------
// Kernel 6/8: transposes (B, PD, T) <-> (B, T, PD), tiled 32x32 via LDS.
// ---------------------------------------------------------------------------
__global__ void k_tin(const float* __restrict__ x, float* __restrict__ y) {
    __shared__ float tile[32][33];
    int b = blockIdx.z;
    int r0 = blockIdx.x * 32;   // PD index
    int t0 = blockIdx.y * 32;   // T index
    int tx = threadIdx.x, ty = threadIdx.y;
    #pragma unroll
    for (int i = ty; i < 32; i += 8) {
        int t = t0 + tx;
        if (t < kT) tile[i][tx] = x[((long long)b * kPD + (r0 + i)) * kT + t];
    }
    __syncthreads();
    #pragma unroll
    for (int i = ty; i < 32; i += 8) {
        int t = t0 + i;
        if (t < kT) y[((long long)b * kT + t) * kPD + (r0 + tx)] = tile[tx][i];
    }
}

__global__ void k_tout(const float* __restrict__ y, float* __restrict__ out) {
    __shared__ float tile[32][33];
    int b = blockIdx.z;
    int r0 = blockIdx.x * 32;
    int t0 = blockIdx.y * 32;
    int tx = threadIdx.x, ty = threadIdx.y;
    #pragma unroll
    for (int i = ty; i < 32; i += 8) {
        int t = t0 + i;
        if (t < kT) tile[i][tx] = y[((long long)b * kT + t) * kPD + (r0 + tx)];
    }
    __syncthreads();
    #pragma unroll
    for (int i = ty; i < 32; i += 8) {
        int t = t0 + tx;
        if (t < kT) out[((long long)b * kPD + (r0 + i)) * kT + t] = tile[tx][i];
    }
}

// ---------------------------------------------------------------------------
// Kernel 7: fused 2-layer GCN, one block (4 waves) per (b,t).
// MFMA 16x16x32 bf16.  Wave w owns output cols d in [32w, 32w+32), all rows.
// Residual y lives in registers (res[6][8], (ty,tx) epilogue mapping).
// LDS: yL/hT (bf16 GEMM operands) unioned with oL (f32 LN staging).
// ---------------------------------------------------------------------------
__global__ __launch_bounds__(256, 2) void k_gcn(float* __restrict__ y,
                                                const bf16_t* __restrict__ adj,
                                                const int* __restrict__ mask,
                                                const bf16_t* __restrict__ wT,
                                                const float* __restrict__ bias,
                                                const float* __restrict__ gamma,
                                                const float* __restrict__ beta) {
    __shared__ __align__(16) char smem[81280];
    bf16_t* yL = (bf16_t*)smem;                 // [96][YS]
    bf16_t* hT = (bf16_t*)(smem + 26112);       // [128][HS]  (h transposed: [d][p])
    float*  oL = (float*)smem;                  // [96][OS]   overlays yL+hT
    bf16_t* aL = (bf16_t*)(smem + 52736);       // [96][AS]
    bf16_t* wC = (bf16_t*)(smem + 72704);       // [128][32]  W^T chunk (n-major)
    float*  mrowf = (float*)(smem + 80896);     // [96]

    const int tid = threadIdx.x;
    const int tx = tid & 15, ty = tid >> 4, tx4 = tx * 4;
    const int lane = tid & 63, w = tid >> 6;
    const int fc = lane & 15, fg = lane >> 4;   // MFMA frag coords
    const int bt = blockIdx.x, b = bt / kT;

    float* ybt = y + (size_t)bt * kPD;
    const bf16_t* abt = adj + (size_t)bt * kPP;

    if (tid < kP) mrowf[tid] = (float)mask[b * kP + tid];

    // stage adj -> aL (bf16, 8B copies)
    #pragma unroll
    for (int k = 0; k < 9; ++k) {
        int e4 = (k * 256 + tid) * 4;
        int p = e4 / kP, q = e4 - p * kP;
        *(bf16x4*)(aL + p * AS + q) = *(const bf16x4*)(abt + e4);
    }

    // stage y -> yL (bf16) and res (f32 residual), epilogue (ty,tx) mapping
    float res[6][8];
    #pragma unroll
    for (int i = 0; i < 6; ++i) {
        int p = ty * 6 + i;
        float4 f0 = *(const float4*)(ybt + p * kD + tx4);
        float4 f1 = *(const float4*)(ybt + p * kD + 64 + tx4);
        res[i][0] = f0.x; res[i][1] = f0.y; res[i][2] = f0.z; res[i][3] = f0.w;
        res[i][4] = f1.x; res[i][5] = f1.y; res[i][6] = f1.z; res[i][7] = f1.w;
        bf16x4 c0 = {(bf16_t)f0.x, (bf16_t)f0.y, (bf16_t)f0.z, (bf16_t)f0.w};
        bf16x4 c1 = {(bf16_t)f1.x, (bf16_t)f1.y, (bf16_t)f1.z, (bf16_t)f1.w};
        *(bf16x4*)(yL + p * YS + tx4) = c0;
        *(bf16x4*)(yL + p * YS + 64 + tx4) = c1;
    }

    for (int l = 0; l < 2; ++l) {
        const bf16_t* wTl = wT + l * kD * kD;

        // ---- GEMM1: h = yL * W  (K=128, 4 chunks of 32) ----
        f32x4 acc[6][2];
        #pragma unroll
        for (int mt = 0; mt < 6; ++mt) {
            acc[mt][0] = {0.f, 0.f, 0.f, 0.f};
            acc[mt][1] = {0.f, 0.f, 0.f, 0.f};
        }
        for (int kt = 0; kt < 4; ++kt) {
            __syncthreads();   // protects initial staging (l=0,kt=0), yL restage (l=1,kt=0), wC reuse
            {
                int n = tid >> 1, ko = (tid & 1) * 16;
                *(bf16x8*)(wC + n * 32 + ko)     = *(const bf16x8*)(wTl + n * kD + kt * 32 + ko);
                *(bf16x8*)(wC + n * 32 + ko + 8) = *(const bf16x8*)(wTl + n * kD + kt * 32 + ko + 8);
            }
            __syncthreads();
            bf16x8 bf0 = *(const bf16x8*)(wC + (w * 32 + fc) * 32 + fg * 8);
            bf16x8 bf1 = *(const bf16x8*)(wC + (w * 32 + 16 + fc) * 32 + fg * 8);
            #pragma unroll
            for (int mt = 0; mt < 6; ++mt) {
                bf16x8 af = *(const bf16x8*)(yL + (mt * 16 + fc) * YS + kt * 32 + fg * 8);
                acc[mt][0] = mfma16(af, bf0, acc[mt][0]);
                acc[mt][1] = mfma16(af, bf1, acc[mt][1]);
            }
        }

        // write h transposed: hT[d][p] (bf16)
        #pragma unroll
        for (int mt = 0; mt < 6; ++mt)
            #pragma unroll
            for (int nn = 0; nn < 2; ++nn) {
                int d = (w * 2 + nn) * 16 + fc;
                int p0 = mt * 16 + fg * 4;
                bf16x4 hv = {(bf16_t)acc[mt][nn][0], (bf16_t)acc[mt][nn][1],
                             (bf16_t)acc[mt][nn][2], (bf16_t)acc[mt][nn][3]};
                *(bf16x4*)(hT + d * HS + p0) = hv;
            }
        __syncthreads();

        // ---- GEMM2: o = aL * h  (K=96, 3 chunks of 32) ----
        f32x4 acc2[6][2];
        #pragma unroll
        for (int mt = 0; mt < 6; ++mt) {
            acc2[mt][0] = {0.f, 0.f, 0.f, 0.f};
            acc2[mt][1] = {0.f, 0.f, 0.f, 0.f};
        }
        #pragma unroll
        for (int kt = 0; kt < 3; ++kt) {
            bf16x8 bf0 = *(const bf16x8*)(hT + (w * 32 + fc) * HS + kt * 32 + fg * 8);
            bf16x8 bf1 = *(const bf16x8*)(hT + (w * 32 + 16 + fc) * HS + kt * 32 + fg * 8);
            #pragma unroll
            for (int mt = 0; mt < 6; ++mt) {
                bf16x8 af = *(const bf16x8*)(aL + (mt * 16 + fc) * AS + kt * 32 + fg * 8);
                acc2[mt][0] = mfma16(af, bf0, acc2[mt][0]);
                acc2[mt][1] = mfma16(af, bf1, acc2[mt][1]);
            }
        }
        __syncthreads();   // all hT/yL reads complete before oL overwrite

        // scatter o -> oL (f32), overlaying yL+hT
        #pragma unroll
        for (int mt = 0; mt < 6; ++mt)
            #pragma unroll
            for (int nn = 0; nn < 2; ++nn) {
                int d = (w * 2 + nn) * 16 + fc;
                int p0 = mt * 16 + fg * 4;
                oL[(p0 + 0) * OS + d] = acc2[mt][nn][0];
                oL[(p0 + 1) * OS + d] = acc2[mt][nn][1];
                oL[(p0 + 2) * OS + d] = acc2[mt][nn][2];
                oL[(p0 + 3) * OS + d] = acc2[mt][nn][3];
            }
        __syncthreads();

        // ---- epilogue: relu+bias+mask, LN over D, residual update ----
        const float* bl = bias + l * kD;
        const float* gl = gamma + l * kD;
        const float* bel = beta + l * kD;
        float4 bb0 = *(const float4*)(bl + tx4), bb1 = *(const float4*)(bl + 64 + tx4);
        float4 gg0 = *(const float4*)(gl + tx4), gg1 = *(const float4*)(gl + 64 + tx4);
        float4 be0 = *(const float4*)(bel + tx4), be1 = *(const float4*)(bel + 64 + tx4);

        #pragma unroll
        for (int i = 0; i < 6; ++i) {
            int p = ty * 6 + i;
            float mpf = mrowf[p];
            float4 o0 = *(const float4*)(oL + p * OS + tx4);
            float4 o1 = *(const float4*)(oL + p * OS + 64 + tx4);
            float v[8];
            v[0] = fmaxf(o0.x + bb0.x, 0.f) * mpf;
            v[1] = fmaxf(o0.y + bb0.y, 0.f) * mpf;
            v[2] = fmaxf(o0.z + bb0.z, 0.f) * mpf;
            v[3] = fmaxf(o0.w + bb0.w, 0.f) * mpf;
            v[4] = fmaxf(o1.x + bb1.x, 0.f) * mpf;
            v[5] = fmaxf(o1.y + bb1.y, 0.f) * mpf;
            v[6] = fmaxf(o1.z + bb1.z, 0.f) * mpf;
            v[7] = fmaxf(o1.w + bb1.w, 0.f) * mpf;

            float s = v[0] + v[1] + v[2] + v[3] + v[4] + v[5] + v[6] + v[7];
            s += __shfl_xor(s, 8);
            s += __shfl_xor(s, 4);
            s += __shfl_xor(s, 2);
            s += __shfl_xor(s, 1);
            float mu = s * 0.0078125f;

            float ss = 0.f;
            #pragma unroll
            for (int j = 0; j < 8; ++j) { float dv = v[j] - mu; ss += dv * dv; }
            ss += __shfl_xor(ss, 8);
            ss += __shfl_xor(ss, 4);
            ss += __shfl_xor(ss, 2);
            ss += __shfl_xor(ss, 1);
            float inv = rsqrtf(ss * 0.0078125f + 1e-5f);

            res[i][0] += (v[0] - mu) * inv * gg0.x + be0.x;
            res[i][1] += (v[1] - mu) * inv * gg0.y + be0.y;
            res[i][2] += (v[2] - mu) * inv * gg0.z + be0.z;
            res[i][3] += (v[3] - mu) * inv * gg0.w + be0.w;
            res[i][4] += (v[4] - mu) * inv * gg1.x + be1.x;
            res[i][5] += (v[5] - mu) * inv * gg1.y + be1.y;
            res[i][6] += (v[6] - mu) * inv * gg1.z + be1.z;
            res[i][7] += (v[7] - mu) * inv * gg1.w + be1.w;
        }
        __syncthreads();   // oL reads done before yL region is rewritten

        if (l == 0) {
            // restage yL (bf16) from updated res for layer 1
            #pragma unroll
            for (int i = 0; i < 6; ++i) {
                int p = ty * 6 + i;
                bf16x4 c0 = {(bf16_t)res[i][0], (bf16_t)res[i][1], (bf16_t)res[i][2], (bf16_t)res[i][3]};
                bf16x4 c1 = {(bf16_t)res[i][4], (bf16_t)res[i][5], (bf16_t)res[i][6], (bf16_t)res[i][7]};
                *(bf16x4*)(yL + p * YS + tx4) = c0;
                *(bf16x4*)(yL + p * YS + 64 + tx4) = c1;
            }
            // next layer's first __syncthreads() (kt=0) protects these writes
        } else {
            #pragma unroll
            for (int i = 0; i < 6; ++i) {
                int p = ty * 6 + i;
                *(float4*)(ybt + p * kD + tx4) =
                    make_float4(res[i][0], res[i][1], res[i][2], res[i][3]);
                *(float4*)(ybt + p * kD + 64 + tx4) =
                    make_float4(res[i][4], res[i][5], res[i][6], res[i][7]);
            }
        }
    }
}

// ---------------------------------------------------------------------------
extern "C" void kernel_launch(void* const* d_in, const int* in_sizes, int n_in,
                              void* d_out, int out_size, void* d_ws, size_t ws_size,
                              hipStream_t stream) {
    (void)in_sizes; (void)n_in; (void)out_size; (void)ws_size;

    const float* x = (const float*)d_in[0];
    const float* dist = (const float*)d_in[1];
    const unsigned char* mraw = (const unsigned char*)d_in[2];
    const float* W = (const float*)d_in[3];
    const float* bias = (const float*)d_in[4];
    const float* gamma = (const float*)d_in[5];
    const float* beta = (const float*)d_in[6];
    float* out = (float*)d_out;

    char* ws = (char*)d_ws;
    double* stats = (double*)ws;                           // 32 B
    float* params = (float*)(ws + 32);                     // 16 B
    int* mask = (int*)(ws + 64);                           // 6144 B
    bf16_t* wT = (bf16_t*)(ws + 8192);                     // 65,536 B
    bf16_t* adj = (bf16_t*)(ws + 81920);                   // 35,389,440 B
    float* y = (float*)(ws + 81920 + (size_t)kBT * kPP * 2);  // 94,371,840 B

    k_mask<<<1, 256, 0, stream>>>(mraw, mask, stats);
    k_prep<<<dim3(64, 2), 256, 0, stream>>>(W, wT);
    k_stats<<<1024, 256, 0, stream>>>(dist, mask, stats);
    k_fin<<<1, 1, 0, stream>>>(stats, params);
    k_adj<<<kBT, 256, 0, stream>>>(dist, mask, params, adj);

    dim3 tgrid(kPD / 32, (kT + 31) / 32, kB);
    dim3 tblk(32, 8);
    k_tin<<<tgrid, tblk, 0, stream>>>(x, y);

    k_gcn<<<kBT, 256, 0, stream>>>(y, adj, mask, wT, bias, gamma, beta);

    k_tout<<<tgrid, tblk, 0, stream>>>(y, out);
}

// Round 3
// 231.415 us; speedup vs baseline: 2.7242x; 1.1084x over previous
//
#include <hip/hip_runtime.h>
#include <math.h>

typedef __bf16 bf16_t;
typedef __bf16 bf16x8 __attribute__((ext_vector_type(8)));
typedef __bf16 bf16x4 __attribute__((ext_vector_type(4)));
typedef float f32x4 __attribute__((ext_vector_type(4)));

namespace {
constexpr int kB = 16;
constexpr int kT = 120;
constexpr int kP = 96;
constexpr int kD = 128;
constexpr int kBT = kB * kT;        // 1920
constexpr int kPP = kP * kP;        // 9216
constexpr int kPD = kP * kD;        // 12288
constexpr long long kND = (long long)kBT * kPP;  // 17,694,720

// LDS strides (bf16 elements)
constexpr int YS = 136;   // yL  [96][136] = 26112 B (16B-aligned rows for b128)
constexpr int HS = 104;   // hT  [128][104] = 26624 B
constexpr int OS = 132;   // oLb [96][132] = 25344 B (8B-aligned rows; scatter hits 32 banks)
constexpr int AS = 104;   // aL  [96][104] = 19968 B
constexpr int UNION_B = 26624;            // max(yL, hT, oLb)
constexpr int AL_OFF = UNION_B;           // 26624
constexpr int MROW_OFF = AL_OFF + 19968;  // 46592
constexpr int SMEM_B = MROW_OFF + 384;    // 46976 -> 3 blocks/CU
}

__device__ __forceinline__ f32x4 mfma16(bf16x8 a, bf16x8 b, f32x4 c) {
    return __builtin_amdgcn_mfma_f32_16x16x32_bf16(a, b, c, 0, 0, 0);
}

// ---------------------------------------------------------------------------
// Kernel 1: canonicalize padding mask (layout-detecting) + zero stats accums.
// ---------------------------------------------------------------------------
__global__ void k_mask(const unsigned char* __restrict__ mraw, int* __restrict__ mask,
                       double* __restrict__ stats) {
    int tid = threadIdx.x;
    if (tid < 4) stats[tid] = 0.0;
    const unsigned int* u32 = (const unsigned int*)mraw;
    unsigned int w0 = u32[0];
    int mode;
    if (w0 == 0x01010101u) mode = 0;       // 1-byte bool
    else if (w0 == 1u) mode = 1;           // int32
    else mode = 2;                          // float32
    for (int i = tid; i < kB * kP; i += blockDim.x) {
        int v;
        if (mode == 0)      v = (mraw[i] != 0);
        else if (mode == 1) v = (u32[i] != 0);
        else                v = (((const float*)mraw)[i] != 0.0f);
        mask[i] = v;
    }
}

// ---------------------------------------------------------------------------
// Kernel 2: W[l][k][n] (f32) -> wT[l][n][k] (bf16)
// ---------------------------------------------------------------------------
__global__ void k_prep(const float* __restrict__ W, bf16_t* __restrict__ wT) {
    int l = blockIdx.y;
    int idx = blockIdx.x * 256 + threadIdx.x;   // 0..16383
    int n = idx >> 7, k = idx & 127;
    wT[l * 16384 + n * 128 + k] = (bf16_t)W[l * 16384 + k * 128 + n];
}

// ---------------------------------------------------------------------------
// Kernel 3: global masked stats over distances (float4 loads, LDS mask).
// ---------------------------------------------------------------------------
__global__ __launch_bounds__(256) void k_stats(const float* __restrict__ dist,
                                               const int* __restrict__ mask,
                                               double* __restrict__ stats) {
    __shared__ int ml[kB * kP];
    for (int i = threadIdx.x; i < kB * kP; i += 256) ml[i] = mask[i];
    __syncthreads();

    long long n4 = kND / 4;
    long long stride = (long long)gridDim.x * 256;
    double s = 0.0, s2 = 0.0;
    int cnt = 0;
    for (long long i4 = (long long)blockIdx.x * 256 + threadIdx.x; i4 < n4; i4 += stride) {
        int q0 = 4 * (int)(i4 % 24);
        long long r = i4 / 24;
        int p = (int)(r % 96);
        int b = (int)((r / 96) / kT);
        const int* mb = ml + b * kP;
        if (mb[p]) {
            float4 d4 = *(const float4*)(dist + i4 * 4);
            if (mb[q0 + 0]) { s += d4.x; s2 += (double)d4.x * d4.x; cnt++; }
            if (mb[q0 + 1]) { s += d4.y; s2 += (double)d4.y * d4.y; cnt++; }
            if (mb[q0 + 2]) { s += d4.z; s2 += (double)d4.z * d4.z; cnt++; }
            if (mb[q0 + 3]) { s += d4.w; s2 += (double)d4.w * d4.w; cnt++; }
        }
    }
    __shared__ double sh[256];
    int tid = threadIdx.x;
    sh[tid] = s; __syncthreads();
    for (int off = 128; off > 0; off >>= 1) { if (tid < off) sh[tid] += sh[tid + off]; __syncthreads(); }
    if (tid == 0) atomicAdd(&stats[0], sh[0]);
    __syncthreads();
    sh[tid] = s2; __syncthreads();
    for (int off = 128; off > 0; off >>= 1) { if (tid < off) sh[tid] += sh[tid + off]; __syncthreads(); }
    if (tid == 0) atomicAdd(&stats[1], sh[0]);
    __syncthreads();
    sh[tid] = (double)cnt; __syncthreads();
    for (int off = 128; off > 0; off >>= 1) { if (tid < off) sh[tid] += sh[tid + off]; __syncthreads(); }
    if (tid == 0) atomicAdd(&stats[2], sh[0]);
}

// ---------------------------------------------------------------------------
// Kernel 4: finalize sigma -> 1/(2*sigma^2)
// ---------------------------------------------------------------------------
__global__ void k_fin(const double* __restrict__ stats, float* __restrict__ params) {
    double n = stats[2];
    double mean = stats[0] / n;
    double var = (stats[1] - n * mean * mean) / (n - 1.0);
    double sigma = sqrt(var) + 1e-8;
    params[0] = (float)(1.0 / (2.0 * sigma * sigma));
}

// ---------------------------------------------------------------------------
// Kernel 5: adjacency build, one block per (b,t). Output bf16.
// ---------------------------------------------------------------------------
__global__ __launch_bounds__(256) void k_adj(const float* __restrict__ dist,
                                             const int* __restrict__ mask,
                                             const float* __restrict__ params,
                                             bf16_t* __restrict__ adj) {
    __shared__ float aT[kP * 97];
    __shared__ float dis[kP];
    __shared__ int mrow[kP];
    int bt = blockIdx.x;
    int b = bt / kT;
    int tid = threadIdx.x;
    if (tid < kP) mrow[tid] = mask[b * kP + tid];
    float inv2s2 = params[0];
    __syncthreads();
    const float* dbt = dist + (long long)bt * kPP;
    #pragma unroll
    for (int k = 0; k < 36; ++k) {
        int e = k * 256 + tid;
        int p = e / kP;
        int q = e - p * kP;
        float d = dbt[e];
        float v = 0.0f;
        if (mrow[p] && mrow[q]) v = __expf(-d * d * inv2s2);
        if (p == q && mrow[p]) v += 1.0f;
        aT[p * 97 + q] = v;
    }
    __syncthreads();
    if (tid < kP) {
        float s = 0.0f;
        for (int q = 0; q < kP; ++q) s += aT[tid * 97 + q];
        s = fmaxf(s, 1e-8f);
        s = fmaxf(s * (float)mrow[tid], 1e-8f);
        dis[tid] = 1.0f / sqrtf(s);
    }
    __syncthreads();
    bf16_t* obt = adj + (long long)bt * kPP;
    #pragma unroll
    for (int k = 0; k < 36; ++k) {
        int e = k * 256 + tid;
        int p = e / kP;
        int q = e - p * kP;
        obt[e] = (bf16_t)(dis[p] * aT[p * 97 + q] * dis[q]);
    }
}

// ---------------------------------------------------------------------------
// Kernel 6: transpose in, (B, PD, T) f32 -> (B, T, PD) bf16
// ---------------------------------------------------------------------------
__global__ void k_tin(const float* __restrict__ x, bf16_t* __restrict__ y) {
    __shared__ float tile[32][33];
    int b = blockIdx.z;
    int r0 = blockIdx.x * 32;   // PD index
    int t0 = blockIdx.y * 32;   // T index
    int tx = threadIdx.x, ty = threadIdx.y;
    #pragma unroll
    for (int i = ty; i < 32; i += 8) {
        int t = t0 + tx;
        if (t < kT) tile[i][tx] = x[((long long)b * kPD + (r0 + i)) * kT + t];
    }
    __syncthreads();
    #pragma unroll
    for (int i = ty; i < 32; i += 8) {
        int t = t0 + i;
        if (t < kT) y[((long long)b * kT + t) * kPD + (r0 + tx)] = (bf16_t)tile[tx][i];
    }
}

// ---------------------------------------------------------------------------
// Kernel 8: transpose out, (B, T, PD) bf16 -> (B, PD, T) f32
// ---------------------------------------------------------------------------
__global__ void k_tout(const bf16_t* __restrict__ y, float* __restrict__ out) {
    __shared__ float tile[32][33];
    int b = blockIdx.z;
    int r0 = blockIdx.x * 32;
    int t0 = blockIdx.y * 32;
    int tx = threadIdx.x, ty = threadIdx.y;
    #pragma unroll
    for (int i = ty; i < 32; i += 8) {
        int t = t0 + i;
        if (t < kT) tile[i][tx] = (float)y[((long long)b * kT + t) * kPD + (r0 + tx)];
    }
    __syncthreads();
    #pragma unroll
    for (int i = ty; i < 32; i += 8) {
        int t = t0 + tx;
        if (t < kT) out[((long long)b * kPD + (r0 + i)) * kT + t] = tile[tx][i];
    }
}

// ---------------------------------------------------------------------------
// Kernel 7: fused 2-layer GCN, one block (4 waves) per (b,t), 3 blocks/CU.
// W fragments live in registers (loaded per layer); yL/hT/oLb overlay one
// LDS union region (phase-separated by barriers); aL persists.
// Wave w owns output cols d in [32w, 32w+32).
// ---------------------------------------------------------------------------
__global__ __launch_bounds__(256, 3) void k_gcn(bf16_t* __restrict__ y,
                                                const bf16_t* __restrict__ adj,
                                                const int* __restrict__ mask,
                                                const bf16_t* __restrict__ wT,
                                                const float* __restrict__ bias,
                                                const float* __restrict__ gamma,
                                                const float* __restrict__ beta) {
    __shared__ __align__(16) char smem[SMEM_B];
    bf16_t* yL  = (bf16_t*)smem;                  // [96][YS]   (union)
    bf16_t* hT  = (bf16_t*)smem;                  // [128][HS]  (union)
    bf16_t* oLb = (bf16_t*)smem;                  // [96][OS]   (union)
    bf16_t* aL  = (bf16_t*)(smem + AL_OFF);       // [96][AS]
    float* mrowf = (float*)(smem + MROW_OFF);     // [96]

    const int tid = threadIdx.x;
    const int tx = tid & 15, ty = tid >> 4;
    const int lane = tid & 63, w = tid >> 6;
    const int fc = lane & 15, fg = lane >> 4;     // MFMA frag coords
    const int bt = blockIdx.x, b = bt / kT;
    const int d0 = tx * 8;                        // epilogue: 8 consecutive d

    bf16_t* ybt = y + (size_t)bt * kPD;
    const bf16_t* abt = adj + (size_t)bt * kPP;

    if (tid < kP) mrowf[tid] = (float)mask[b * kP + tid];

    // stage adj -> aL
    #pragma unroll
    for (int k = 0; k < 9; ++k) {
        int e4 = (k * 256 + tid) * 4;
        int p = e4 / kP, q = e4 - p * kP;
        *(bf16x4*)(aL + p * AS + q) = *(const bf16x4*)(abt + e4);
    }

    // stage y -> yL and res (f32 residual); row p = ty*6+i, cols d0..d0+7
    float res[6][8];
    #pragma unroll
    for (int i = 0; i < 6; ++i) {
        int p = ty * 6 + i;
        bf16x8 v = *(const bf16x8*)(ybt + p * kD + d0);
        #pragma unroll
        for (int j = 0; j < 8; ++j) res[i][j] = (float)v[j];
        *(bf16x8*)(yL + p * YS + d0) = v;
    }

    for (int l = 0; l < 2; ++l) {
        // W fragments -> registers (before barrier; overlaps with it)
        const bf16_t* wTl = wT + l * kD * kD;
        bf16x8 wf[4][2];
        #pragma unroll
        for (int kt = 0; kt < 4; ++kt) {
            wf[kt][0] = *(const bf16x8*)(wTl + (w * 32 + fc) * kD + kt * 32 + fg * 8);
            wf[kt][1] = *(const bf16x8*)(wTl + (w * 32 + 16 + fc) * kD + kt * 32 + fg * 8);
        }
        __syncthreads();   // [S1] yL (and aL, l=0) ready

        // ---- GEMM1: h = yL * W  (K=128), no barriers inside ----
        f32x4 acc[6][2];
        #pragma unroll
        for (int mt = 0; mt < 6; ++mt) { acc[mt][0] = {0,0,0,0}; acc[mt][1] = {0,0,0,0}; }
        #pragma unroll
        for (int kt = 0; kt < 4; ++kt) {
            #pragma unroll
            for (int mt = 0; mt < 6; ++mt) {
                bf16x8 af = *(const bf16x8*)(yL + (mt * 16 + fc) * YS + kt * 32 + fg * 8);
                acc[mt][0] = mfma16(af, wf[kt][0], acc[mt][0]);
                acc[mt][1] = mfma16(af, wf[kt][1], acc[mt][1]);
            }
        }
        __syncthreads();   // [S2] yL reads done before hT overlay

        // write h transposed: hT[e][p]
        #pragma unroll
        for (int mt = 0; mt < 6; ++mt)
            #pragma unroll
            for (int nn = 0; nn < 2; ++nn) {
                int e = (w * 2 + nn) * 16 + fc;
                int p0 = mt * 16 + fg * 4;
                bf16x4 hv = {(bf16_t)acc[mt][nn][0], (bf16_t)acc[mt][nn][1],
                             (bf16_t)acc[mt][nn][2], (bf16_t)acc[mt][nn][3]};
                *(bf16x4*)(hT + e * HS + p0) = hv;
            }
        __syncthreads();   // [S3] hT ready

        // ---- GEMM2: o = aL * h^T  (K=96) ----
        f32x4 acc2[6][2];
        #pragma unroll
        for (int mt = 0; mt < 6; ++mt) { acc2[mt][0] = {0,0,0,0}; acc2[mt][1] = {0,0,0,0}; }
        #pragma unroll
        for (int kt = 0; kt < 3; ++kt) {
            bf16x8 bf0 = *(const bf16x8*)(hT + (w * 32 + fc) * HS + kt * 32 + fg * 8);
            bf16x8 bf1 = *(const bf16x8*)(hT + (w * 32 + 16 + fc) * HS + kt * 32 + fg * 8);
            #pragma unroll
            for (int mt = 0; mt < 6; ++mt) {
                bf16x8 af = *(const bf16x8*)(aL + (mt * 16 + fc) * AS + kt * 32 + fg * 8);
                acc2[mt][0] = mfma16(af, bf0, acc2[mt][0]);
                acc2[mt][1] = mfma16(af, bf1, acc2[mt][1]);
            }
        }
        __syncthreads();   // [S4] hT reads done before oLb overlay

        // scatter o -> oLb (bf16)
        #pragma unroll
        for (int mt = 0; mt < 6; ++mt)
            #pragma unroll
            for (int nn = 0; nn < 2; ++nn) {
                int d = (w * 2 + nn) * 16 + fc;
                int p0 = mt * 16 + fg * 4;
                oLb[(p0 + 0) * OS + d] = (bf16_t)acc2[mt][nn][0];
                oLb[(p0 + 1) * OS + d] = (bf16_t)acc2[mt][nn][1];
                oLb[(p0 + 2) * OS + d] = (bf16_t)acc2[mt][nn][2];
                oLb[(p0 + 3) * OS + d] = (bf16_t)acc2[mt][nn][3];
            }
        __syncthreads();   // [S5] oLb ready

        // ---- epilogue: relu+bias+mask, LN over D, residual update ----
        const float* bl = bias + l * kD;
        const float* gl = gamma + l * kD;
        const float* bel = beta + l * kD;
        float4 bb0 = *(const float4*)(bl + d0), bb1 = *(const float4*)(bl + d0 + 4);
        float4 gg0 = *(const float4*)(gl + d0), gg1 = *(const float4*)(gl + d0 + 4);
        float4 be0 = *(const float4*)(bel + d0), be1 = *(const float4*)(bel + d0 + 4);
        float bb[8] = {bb0.x, bb0.y, bb0.z, bb0.w, bb1.x, bb1.y, bb1.z, bb1.w};
        float gg[8] = {gg0.x, gg0.y, gg0.z, gg0.w, gg1.x, gg1.y, gg1.z, gg1.w};
        float be[8] = {be0.x, be0.y, be0.z, be0.w, be1.x, be1.y, be1.z, be1.w};

        #pragma unroll
        for (int i = 0; i < 6; ++i) {
            int p = ty * 6 + i;
            float mpf = mrowf[p];
            bf16x4 o0 = *(const bf16x4*)(oLb + p * OS + d0);
            bf16x4 o1 = *(const bf16x4*)(oLb + p * OS + d0 + 4);
            float v[8];
            #pragma unroll
            for (int j = 0; j < 4; ++j) {
                v[j]     = fmaxf((float)o0[j] + bb[j], 0.f) * mpf;
                v[j + 4] = fmaxf((float)o1[j] + bb[j + 4], 0.f) * mpf;
            }
            float s = v[0] + v[1] + v[2] + v[3] + v[4] + v[5] + v[6] + v[7];
            s += __shfl_xor(s, 8);
            s += __shfl_xor(s, 4);
            s += __shfl_xor(s, 2);
            s += __shfl_xor(s, 1);
            float mu = s * 0.0078125f;

            float ss = 0.f;
            #pragma unroll
            for (int j = 0; j < 8; ++j) { float dv = v[j] - mu; ss += dv * dv; }
            ss += __shfl_xor(ss, 8);
            ss += __shfl_xor(ss, 4);
            ss += __shfl_xor(ss, 2);
            ss += __shfl_xor(ss, 1);
            float inv = rsqrtf(ss * 0.0078125f + 1e-5f);

            #pragma unroll
            for (int j = 0; j < 8; ++j)
                res[i][j] += (v[j] - mu) * inv * gg[j] + be[j];
        }

        if (l == 0) {
            __syncthreads();   // [S6] oLb reads done before yL overlay restage
            #pragma unroll
            for (int i = 0; i < 6; ++i) {
                int p = ty * 6 + i;
                bf16x8 c;
                #pragma unroll
                for (int j = 0; j < 8; ++j) c[j] = (bf16_t)res[i][j];
                *(bf16x8*)(yL + p * YS + d0) = c;
            }
            // next layer's [S1] makes these visible
        } else {
            #pragma unroll
            for (int i = 0; i < 6; ++i) {
                int p = ty * 6 + i;
                bf16x8 c;
                #pragma unroll
                for (int j = 0; j < 8; ++j) c[j] = (bf16_t)res[i][j];
                *(bf16x8*)(ybt + p * kD + d0) = c;
            }
        }
    }
}

// ---------------------------------------------------------------------------
extern "C" void kernel_launch(void* const* d_in, const int* in_sizes, int n_in,
                              void* d_out, int out_size, void* d_ws, size_t ws_size,
                              hipStream_t stream) {
    (void)in_sizes; (void)n_in; (void)out_size; (void)ws_size;

    const float* x = (const float*)d_in[0];
    const float* dist = (const float*)d_in[1];
    const unsigned char* mraw = (const unsigned char*)d_in[2];
    const float* W = (const float*)d_in[3];
    const float* bias = (const float*)d_in[4];
    const float* gamma = (const float*)d_in[5];
    const float* beta = (const float*)d_in[6];
    float* out = (float*)d_out;

    char* ws = (char*)d_ws;
    double* stats = (double*)ws;                            // 32 B
    float* params = (float*)(ws + 32);                      // 16 B
    int* mask = (int*)(ws + 64);                            // 6144 B
    bf16_t* wT = (bf16_t*)(ws + 8192);                      // 65,536 B
    bf16_t* adj = (bf16_t*)(ws + 81920);                    // 35,389,440 B
    bf16_t* y = (bf16_t*)(ws + 81920 + (size_t)kBT * kPP * 2);  // 47,185,920 B

    k_mask<<<1, 256, 0, stream>>>(mraw, mask, stats);
    k_prep<<<dim3(64, 2), 256, 0, stream>>>(W, wT);
    k_stats<<<1024, 256, 0, stream>>>(dist, mask, stats);
    k_fin<<<1, 1, 0, stream>>>(stats, params);
    k_adj<<<kBT, 256, 0, stream>>>(dist, mask, params, adj);

    dim3 tgrid(kPD / 32, (kT + 31) / 32, kB);
    dim3 tblk(32, 8);
    k_tin<<<tgrid, tblk, 0, stream>>>(x, y);

    k_gcn<<<kBT, 256, 0, stream>>>(y, adj, mask, wT, bias, gamma, beta);

    k_tout<<<tgrid, tblk, 0, stream>>>(y, out);
}